// Round 6
// baseline (1435.063 us; speedup 1.0000x reference)
//
#include <hip/hip_runtime.h>

#define NLAT 721
#define NLON 1440
#define NB 4
#define ND 5
#define NROWS (NLAT*ND)          // 3605
#define PLANE (NLAT*NLON)        // 1,038,240
#define HVOL (NB*PLANE)          // 4,152,960
#define DTSTEP 0.01f
#define TAPCAP 262144
#define PITCH 361                // LDS row pitch per residue class (360 + 1)
#define WCH 384                  // weight chunk (multiple of 4, == blockDim)

// ---------------------------------------------------------------------------
// Kernel A: per (lat,d) row, find the wrapped-interval support [jlo, jhi]
// ---------------------------------------------------------------------------
__global__ __launch_bounds__(64) void support_kernel(
    const float* __restrict__ Kgc, const float* __restrict__ Kgs,
    const float* __restrict__ Kdc, const float* __restrict__ Kds,
    int* __restrict__ jlo_a, int* __restrict__ cnt_a)
{
  int row = blockIdx.x;
  int lane = threadIdx.x;
  const float* a = Kgc + (size_t)row * NLON;
  const float* b = Kgs + (size_t)row * NLON;
  const float* c = Kdc + (size_t)row * NLON;
  const float* d = Kds + (size_t)row * NLON;
  int jmin = 1 << 30, jmax = -(1 << 30);
  for (int m = lane; m < NLON; m += 64) {
    float s = fabsf(a[m]) + fabsf(b[m]) + fabsf(c[m]) + fabsf(d[m]);
    if (s != 0.0f) {
      int j = (m >= NLON / 2) ? (m - NLON) : m;
      jmin = min(jmin, j);
      jmax = max(jmax, j);
    }
  }
  for (int s = 32; s > 0; s >>= 1) {
    jmin = min(jmin, __shfl_down(jmin, s));
    jmax = max(jmax, __shfl_down(jmax, s));
  }
  if (lane == 0) {
    if (jmax < jmin) { jlo_a[row] = 0; cnt_a[row] = 0; }
    else             { jlo_a[row] = jmin; cnt_a[row] = jmax - jmin + 1; }
  }
}

// ---------------------------------------------------------------------------
// Kernel B: prefix sum over 4-padded row counts; per-row meta
// int4(iq*NLON, qm = jlo mod 1440, cnt4, pool offset).
// ---------------------------------------------------------------------------
__global__ __launch_bounds__(256) void scan_kernel(
    const int* __restrict__ cnt_a, const int* __restrict__ jlo_a,
    int* __restrict__ off_a, int4* __restrict__ rowmeta, int tap_cap)
{
  __shared__ int buf[256];
  __shared__ int carry;
  int tid = threadIdx.x;
  if (tid == 0) carry = 0;
  __syncthreads();
  for (int base = 0; base < NROWS; base += 256) {
    int i = base + tid;
    int v = (i < NROWS) ? ((cnt_a[i] + 3) & ~3) : 0;
    buf[tid] = v;
    __syncthreads();
    for (int s = 1; s < 256; s <<= 1) {
      int t = (tid >= s) ? buf[tid - s] : 0;
      __syncthreads();
      buf[tid] += t;
      __syncthreads();
    }
    if (i < NROWS) off_a[i] = carry + buf[tid] - v;   // exclusive
    __syncthreads();
    if (tid == 255) carry += buf[255];
    __syncthreads();
  }
  __syncthreads();
  for (int r = tid; r < NROWS; r += 256) {
    int off = off_a[r];
    int c4  = (cnt_a[r] + 3) & ~3;
    if (off >= tap_cap)           c4 = 0;
    else if (off + c4 > tap_cap)  c4 = (tap_cap - off) & ~3;
    int l = r / ND, d = r - ND * l;
    int iq = min(max(l + d - 2, 0), NLAT - 1);
    int jlo = jlo_a[r];
    int qm = jlo + ((jlo < 0) ? NLON : 0);
    rowmeta[r] = make_int4(iq * NLON, qm, c4, off);
  }
}

// ---------------------------------------------------------------------------
// Kernel C: fill weight pool (Kg_c, Kg_s, Kd_c, Kd_s), zero-padded to x4.
// ---------------------------------------------------------------------------
__global__ __launch_bounds__(64) void fill_kernel(
    const float* __restrict__ Kgc, const float* __restrict__ Kgs,
    const float* __restrict__ Kdc, const float* __restrict__ Kds,
    const int* __restrict__ jlo_a, const int* __restrict__ cnt_a,
    const int* __restrict__ off_a,
    float4* __restrict__ tapw, int tap_cap)
{
  int row = blockIdx.x;
  int jlo = jlo_a[row], cnt = cnt_a[row], off = off_a[row];
  int cnt4 = (cnt + 3) & ~3;
  for (int t = threadIdx.x; t < cnt4; t += 64) {
    int p = off + t;
    if (p >= tap_cap) break;
    float4 w = make_float4(0.f, 0.f, 0.f, 0.f);
    if (t < cnt) {
      int j = jlo + t;
      int m = j + ((j < 0) ? NLON : 0);
      size_t idx = (size_t)row * NLON + m;
      w = make_float4(Kgc[idx], Kgs[idx], Kdc[idx], Kds[idx]);
    }
    tapw[p] = w;
  }
}

// ---------------------------------------------------------------------------
// Stage kernel: one block (384 thr) per (lat,batch); thread owns 4 consecutive
// lons (1440 = 4*360; threads 360..383 idle).  Per row: stage full x-row in
// LDS de-interleaved mod 4 (X[m&3][m>>2], pitch 361), then taps via sliding
// 4-element register window: 1 ds_read_b128 + 16 FMA per tap.  Weights
// chunk-staged (broadcast reads).  Center row (d=2) staged last -> epilogue
// reads own-point u,v,h from LDS.
// mode 0: O = S0 + cdt*k ; mode 1: O = (X1+2*X2+X3-S0)/3 + (DT/6)*k4
// ---------------------------------------------------------------------------
__global__ __launch_bounds__(384, 6) void stage_kernel(
    const float* __restrict__ Xh,  const float* __restrict__ Xuv,
    const float* __restrict__ S0h, const float* __restrict__ S0uv,
    const float* __restrict__ X1h, const float* __restrict__ X1uv,
    const float* __restrict__ X2h, const float* __restrict__ X2uv,
    const float* __restrict__ fcor,
    const int4* __restrict__ rowmeta, const float4* __restrict__ tapw,
    float* __restrict__ Oh, float* __restrict__ Ouv,
    float cdt, int mode)
{
  __shared__ float4 sX[4 * PITCH];   // de-interleaved x row (h,u,v,-)
  __shared__ float4 swt[WCH];        // weight chunk

  int y  = blockIdx.x;
  int ly = y >> 2;                   // NB == 4
  int b  = y & 3;
  int l  = (ly & 1) ? (NLAT - 1 - (ly >> 1)) : (ly >> 1);   // heavy-first
  int tid = threadIdx.x;
  bool act = tid < 360;

  const float* __restrict__ xh  = Xh  + (size_t)b * PLANE;
  const float* __restrict__ xuv = Xuv + (size_t)b * PLANE * 2;

  float ah0 = 0.f, ah1 = 0.f, ah2 = 0.f, ah3 = 0.f;
  float au0 = 0.f, au1 = 0.f, au2 = 0.f, au3 = 0.f;
  float av0 = 0.f, av1 = 0.f, av2 = 0.f, av3 = 0.f;

  const int dorder[ND] = {0, 1, 3, 4, 2};   // center row last (epilogue reads it)

  for (int ri = 0; ri < ND; ++ri) {
    int dd = dorder[ri];
    int4 rm = rowmeta[l * ND + dd];          // (iq*NLON, qm, cnt4, off)
    int rcnt = rm.z;
    if (rcnt == 0 && dd != 2) continue;      // block-uniform

    // ---- stage row iq into LDS, de-interleaved mod 4 ----
    __syncthreads();                          // prior row's readers done
    {
      const float* __restrict__ grh  = xh  + rm.x;
      const float* __restrict__ gruv = xuv + 2 * (size_t)rm.x;
      for (int e = tid; e < NLON; e += 384) {
        float  hh = grh[e];
        float2 uv = *(const float2*)(gruv + 2 * e);
        sX[(e & 3) * PITCH + (e >> 2)] = make_float4(hh, uv.x, uv.y, 0.f);
      }
    }
    __syncthreads();

    if (rcnt == 0) continue;

    // ---- init sliding window: elements m0..m0+3, m0 = 4*tid + qm (mod 1440)
    int qm = rm.y;
    int c  = qm & 3;            // uniform
    int u  = qm >> 2;           // uniform, in [0,360)
    float4 w0, w1, w2, w3;
    if (act) {
      #pragma unroll
      for (int d0 = 0; d0 < 4; ++d0) {
        int cc = (c + d0) & 3;
        int uu = u + ((c + d0) >> 2);
        int id = tid + uu; id -= (id >= 360) ? 360 : 0;
        float4 v = sX[cc * PITCH + id];
        if (d0 == 0) w0 = v; else if (d0 == 1) w1 = v;
        else if (d0 == 2) w2 = v; else w3 = v;
      }
    }
    int cl = c;                 // class of next element to load (m0+4)
    int ul = u + 1; ul -= (ul >= 360) ? 360 : 0;

    // ---- weight chunks ----
    for (int tc = 0; tc < rcnt; tc += WCH) {
      int wn = min(WCH, rcnt - tc);
      __syncthreads();
      if (tid < wn) swt[tid] = tapw[rm.w + tc + tid];
      __syncthreads();
      if (act) {
        for (int t = 0; t < wn; t += 4) {
          #pragma unroll
          for (int s = 0; s < 4; ++s) {
            float4 w = swt[t + s];
            ah0 = fmaf(w.z, w0.y, ah0); ah1 = fmaf(w.z, w1.y, ah1);
            ah2 = fmaf(w.z, w2.y, ah2); ah3 = fmaf(w.z, w3.y, ah3);
            ah0 = fmaf(w.w, w0.z, ah0); ah1 = fmaf(w.w, w1.z, ah1);
            ah2 = fmaf(w.w, w2.z, ah2); ah3 = fmaf(w.w, w3.z, ah3);
            au0 = fmaf(w.x, w0.x, au0); au1 = fmaf(w.x, w1.x, au1);
            au2 = fmaf(w.x, w2.x, au2); au3 = fmaf(w.x, w3.x, au3);
            av0 = fmaf(w.y, w0.x, av0); av1 = fmaf(w.y, w1.x, av1);
            av2 = fmaf(w.y, w2.x, av2); av3 = fmaf(w.y, w3.x, av3);
            // slide window: load element m0+4+(t+s)
            int id = tid + ul; id -= (id >= 360) ? 360 : 0;
            float4 nw = sX[cl * PITCH + id];
            w0 = w1; w1 = w2; w2 = w3; w3 = nw;
            ul += (cl == 3) ? 1 : 0; cl = (cl + 1) & 3;
            ul -= (ul >= 360) ? 360 : 0;
          }
        }
      }
    }
  }

  // ---- epilogue: own-point (row l resident in sX), Coriolis, RK4 ----
  if (act) {
    float4 o0 = sX[0 * PITCH + tid];
    float4 o1 = sX[1 * PITCH + tid];
    float4 o2 = sX[2 * PITCH + tid];
    float4 o3 = sX[3 * PITCH + tid];
    float f = fcor[l];
    float kh0 = -ah0, kh1 = -ah1, kh2 = -ah2, kh3 = -ah3;
    float ku0 = fmaf(-f, o0.z, -au0), ku1 = fmaf(-f, o1.z, -au1);
    float ku2 = fmaf(-f, o2.z, -au2), ku3 = fmaf(-f, o3.z, -au3);
    float kv0 = fmaf(f, o0.y, -av0), kv1 = fmaf(f, o1.y, -av1);
    float kv2 = fmaf(f, o2.y, -av2), kv3 = fmaf(f, o3.y, -av3);

    size_t ih  = (size_t)b * PLANE + (size_t)l * NLON + 4 * tid;
    size_t iuv = 2 * ih;
    if (mode == 0) {
      float4 s0 = *(const float4*)(S0h + ih);
      *(float4*)(Oh + ih) = make_float4(fmaf(cdt, kh0, s0.x), fmaf(cdt, kh1, s0.y),
                                        fmaf(cdt, kh2, s0.z), fmaf(cdt, kh3, s0.w));
      float4 sa = *(const float4*)(S0uv + iuv);
      float4 sb = *(const float4*)(S0uv + iuv + 4);
      *(float4*)(Ouv + iuv)     = make_float4(fmaf(cdt, ku0, sa.x), fmaf(cdt, kv0, sa.y),
                                              fmaf(cdt, ku1, sa.z), fmaf(cdt, kv1, sa.w));
      *(float4*)(Ouv + iuv + 4) = make_float4(fmaf(cdt, ku2, sb.x), fmaf(cdt, kv2, sb.y),
                                              fmaf(cdt, ku3, sb.z), fmaf(cdt, kv3, sb.w));
    } else {
      const float DT6 = DTSTEP / 6.0f;
      const float TH  = 1.0f / 3.0f;
      float4 s0 = *(const float4*)(S0h + ih);
      float4 x1 = *(const float4*)(X1h + ih);
      float4 x2 = *(const float4*)(X2h + ih);
      *(float4*)(Oh + ih) = make_float4(
        TH * (x1.x + 2.f * x2.x + o0.x - s0.x) + DT6 * kh0,
        TH * (x1.y + 2.f * x2.y + o1.x - s0.y) + DT6 * kh1,
        TH * (x1.z + 2.f * x2.z + o2.x - s0.z) + DT6 * kh2,
        TH * (x1.w + 2.f * x2.w + o3.x - s0.w) + DT6 * kh3);
      float4 sa = *(const float4*)(S0uv + iuv);
      float4 sb = *(const float4*)(S0uv + iuv + 4);
      float4 xa1 = *(const float4*)(X1uv + iuv);
      float4 xb1 = *(const float4*)(X1uv + iuv + 4);
      float4 xa2 = *(const float4*)(X2uv + iuv);
      float4 xb2 = *(const float4*)(X2uv + iuv + 4);
      *(float4*)(Ouv + iuv) = make_float4(
        TH * (xa1.x + 2.f * xa2.x + o0.y - sa.x) + DT6 * ku0,
        TH * (xa1.y + 2.f * xa2.y + o0.z - sa.y) + DT6 * kv0,
        TH * (xa1.z + 2.f * xa2.z + o1.y - sa.z) + DT6 * ku1,
        TH * (xa1.w + 2.f * xa2.w + o1.z - sa.w) + DT6 * kv1);
      *(float4*)(Ouv + iuv + 4) = make_float4(
        TH * (xb1.x + 2.f * xb2.x + o2.y - sb.x) + DT6 * ku2,
        TH * (xb1.y + 2.f * xb2.y + o2.z - sb.y) + DT6 * kv2,
        TH * (xb1.z + 2.f * xb2.z + o3.y - sb.z) + DT6 * ku3,
        TH * (xb1.w + 2.f * xb2.w + o3.z - sb.w) + DT6 * kv3);
    }
  }
}

// ---------------------------------------------------------------------------
extern "C" void kernel_launch(void* const* d_in, const int* in_sizes, int n_in,
                              void* d_out, int out_size, void* d_ws, size_t ws_size,
                              hipStream_t stream)
{
  const float* h0   = (const float*)d_in[0];
  const float* uv0  = (const float*)d_in[1];
  const float* Kgc  = (const float*)d_in[2];
  const float* Kgs  = (const float*)d_in[3];
  const float* Kdc  = (const float*)d_in[4];
  const float* Kds  = (const float*)d_in[5];
  const float* fcor = (const float*)d_in[6];

  char* ws = (char*)d_ws;
  size_t pos = 0;
  auto carve = [&](size_t bytes) -> void* {
    void* p = ws + pos;
    pos += (bytes + 255) & ~(size_t)255;
    return p;
  };

  int*   jlo_a   = (int*)carve(sizeof(int) * NROWS);
  int*   cnt_a   = (int*)carve(sizeof(int) * NROWS);
  int*   off_a   = (int*)carve(sizeof(int) * NROWS);
  int4*  rowmeta = (int4*)carve(sizeof(int4) * NROWS);
  float* X1      = (float*)carve(sizeof(float) * 3 * (size_t)HVOL);
  float* X2      = (float*)carve(sizeof(float) * 3 * (size_t)HVOL);
  float* X3      = (float*)carve(sizeof(float) * 3 * (size_t)HVOL);
  float4* tapw   = (float4*)carve(sizeof(float4) * (size_t)TAPCAP);

  float* X1h = X1;  float* X1uv = X1 + HVOL;
  float* X2h = X2;  float* X2uv = X2 + HVOL;
  float* X3h = X3;  float* X3uv = X3 + HVOL;
  float* out_h  = (float*)d_out;          // [NB,1,NLAT,NLON]
  float* out_uv = (float*)d_out + HVOL;   // [NB,1,NLAT,NLON,2]

  support_kernel<<<NROWS, 64, 0, stream>>>(Kgc, Kgs, Kdc, Kds, jlo_a, cnt_a);
  scan_kernel<<<1, 256, 0, stream>>>(cnt_a, jlo_a, off_a, rowmeta, TAPCAP);
  fill_kernel<<<NROWS, 64, 0, stream>>>(Kgc, Kgs, Kdc, Kds, jlo_a, cnt_a, off_a,
                                        tapw, TAPCAP);

  dim3 gs(NLAT * NB);

  // stage 1: k1 from S0; X1 = S0 + dt/2 k1
  stage_kernel<<<gs, 384, 0, stream>>>(h0, uv0, h0, uv0, h0, uv0, h0, uv0, fcor,
                                       rowmeta, tapw, X1h, X1uv, 0.5f * DTSTEP, 0);
  // stage 2: k2 from X1; X2 = S0 + dt/2 k2
  stage_kernel<<<gs, 384, 0, stream>>>(X1h, X1uv, h0, uv0, h0, uv0, h0, uv0, fcor,
                                       rowmeta, tapw, X2h, X2uv, 0.5f * DTSTEP, 0);
  // stage 3: k3 from X2; X3 = S0 + dt k3
  stage_kernel<<<gs, 384, 0, stream>>>(X2h, X2uv, h0, uv0, h0, uv0, h0, uv0, fcor,
                                       rowmeta, tapw, X3h, X3uv, DTSTEP, 0);
  // stage 4: k4 from X3; out = (X1 + 2 X2 + X3 - S0)/3 + dt/6 k4
  stage_kernel<<<gs, 384, 0, stream>>>(X3h, X3uv, h0, uv0, X1h, X1uv, X2h, X2uv, fcor,
                                       rowmeta, tapw, out_h, out_uv, 0.0f, 1);
}

// Round 7
// 989.349 us; speedup vs baseline: 1.4505x; 1.4505x over previous
//
#include <hip/hip_runtime.h>

#define NLAT 721
#define NLON 1440
#define NB 4
#define ND 5
#define NROWS (NLAT*ND)          // 3605
#define PLANE (NLAT*NLON)        // 1,038,240
#define HVOL (NB*PLANE)          // 4,152,960
#define DTSTEP 0.01f
#define TAPCAP 262144
#define TCH 256                  // taps per chunk (multiple of 4)
#define NCOLS 720                // lon columns per block
#define BT 192                   // block threads (3 waves)
#define ACT 180                  // compute threads (x4 cols = 720)
#define SH_SZ (NCOLS + TCH + 8)  // 984 floats per LDS array

// ---------------------------------------------------------------------------
// Kernel A: per (lat,d) row, find the wrapped-interval support [jlo, jhi]
// ---------------------------------------------------------------------------
__global__ __launch_bounds__(64) void support_kernel(
    const float* __restrict__ Kgc, const float* __restrict__ Kgs,
    const float* __restrict__ Kdc, const float* __restrict__ Kds,
    int* __restrict__ jlo_a, int* __restrict__ cnt_a)
{
  int row = blockIdx.x;
  int lane = threadIdx.x;
  const float* a = Kgc + (size_t)row * NLON;
  const float* b = Kgs + (size_t)row * NLON;
  const float* c = Kdc + (size_t)row * NLON;
  const float* d = Kds + (size_t)row * NLON;
  int jmin = 1 << 30, jmax = -(1 << 30);
  for (int m = lane; m < NLON; m += 64) {
    float s = fabsf(a[m]) + fabsf(b[m]) + fabsf(c[m]) + fabsf(d[m]);
    if (s != 0.0f) {
      int j = (m >= NLON / 2) ? (m - NLON) : m;
      jmin = min(jmin, j);
      jmax = max(jmax, j);
    }
  }
  for (int s = 32; s > 0; s >>= 1) {
    jmin = min(jmin, __shfl_down(jmin, s));
    jmax = max(jmax, __shfl_down(jmax, s));
  }
  if (lane == 0) {
    if (jmax < jmin) { jlo_a[row] = 0; cnt_a[row] = 0; }
    else             { jlo_a[row] = jmin; cnt_a[row] = jmax - jmin + 1; }
  }
}

// ---------------------------------------------------------------------------
// Kernel B: prefix sum over 4-padded row counts; per-row meta
// int4(iq*NLON, jlo (signed), cnt4, pool offset).
// ---------------------------------------------------------------------------
__global__ __launch_bounds__(256) void scan_kernel(
    const int* __restrict__ cnt_a, const int* __restrict__ jlo_a,
    int* __restrict__ off_a, int4* __restrict__ rowmeta, int tap_cap)
{
  __shared__ int buf[256];
  __shared__ int carry;
  int tid = threadIdx.x;
  if (tid == 0) carry = 0;
  __syncthreads();
  for (int base = 0; base < NROWS; base += 256) {
    int i = base + tid;
    int v = (i < NROWS) ? ((cnt_a[i] + 3) & ~3) : 0;
    buf[tid] = v;
    __syncthreads();
    for (int s = 1; s < 256; s <<= 1) {
      int t = (tid >= s) ? buf[tid - s] : 0;
      __syncthreads();
      buf[tid] += t;
      __syncthreads();
    }
    if (i < NROWS) off_a[i] = carry + buf[tid] - v;   // exclusive
    __syncthreads();
    if (tid == 255) carry += buf[255];
    __syncthreads();
  }
  __syncthreads();
  for (int r = tid; r < NROWS; r += 256) {
    int off = off_a[r];
    int c4  = (cnt_a[r] + 3) & ~3;
    if (off >= tap_cap)           c4 = 0;
    else if (off + c4 > tap_cap)  c4 = (tap_cap - off) & ~3;
    int l = r / ND, d = r - ND * l;
    int iq = min(max(l + d - 2, 0), NLAT - 1);
    rowmeta[r] = make_int4(iq * NLON, jlo_a[r], c4, off);
  }
}

// ---------------------------------------------------------------------------
// Kernel C: fill weight pool (Kg_c, Kg_s, Kd_c, Kd_s), zero-padded to x4.
// ---------------------------------------------------------------------------
__global__ __launch_bounds__(64) void fill_kernel(
    const float* __restrict__ Kgc, const float* __restrict__ Kgs,
    const float* __restrict__ Kdc, const float* __restrict__ Kds,
    const int* __restrict__ jlo_a, const int* __restrict__ cnt_a,
    const int* __restrict__ off_a,
    float4* __restrict__ tapw, int tap_cap)
{
  int row = blockIdx.x;
  int jlo = jlo_a[row], cnt = cnt_a[row], off = off_a[row];
  int cnt4 = (cnt + 3) & ~3;
  for (int t = threadIdx.x; t < cnt4; t += 64) {
    int p = off + t;
    if (p >= tap_cap) break;
    float4 w = make_float4(0.f, 0.f, 0.f, 0.f);
    if (t < cnt) {
      int j = jlo + t;
      int m = j + ((j < 0) ? NLON : 0);
      size_t idx = (size_t)row * NLON + m;
      w = make_float4(Kgc[idx], Kgs[idx], Kdc[idx], Kds[idx]);
    }
    tapw[p] = w;
  }
}

// ---------------------------------------------------------------------------
// Stage kernel.  Grid (2, NLAT*NB), block 192 (180 compute threads x 4 cols).
// Per (row, 256-tap chunk): stage linear x-window [gs0, gs0+719+wcnt] into
// scalar LDS arrays (conflict-free), weights chunk into LDS float4
// (broadcast reads).  Tap loop: 4-tap unrolled register window — per 4 taps:
// 12 ds_read_b32 + 4 weight reads + 64 FMA, static offsets, no wrap logic.
// mode 0: O = S0 + cdt*k ; mode 1: O = (X1+2*X2+X3-S0)/3 + (DT/6)*k4
// ---------------------------------------------------------------------------
__global__ __launch_bounds__(BT, 6) void stage_kernel(
    const float* __restrict__ Xh,  const float* __restrict__ Xuv,
    const float* __restrict__ S0h, const float* __restrict__ S0uv,
    const float* __restrict__ X1h, const float* __restrict__ X1uv,
    const float* __restrict__ X2h, const float* __restrict__ X2uv,
    const float* __restrict__ fcor,
    const int4* __restrict__ rowmeta, const float4* __restrict__ tapw,
    float* __restrict__ Oh, float* __restrict__ Ouv,
    float cdt, int mode)
{
  __shared__ float  sh[SH_SZ];
  __shared__ float  su[SH_SZ];
  __shared__ float  sv[SH_SZ];
  __shared__ float4 swt[TCH];

  int y  = blockIdx.y;
  int ly = y >> 2;                   // NB == 4
  int b  = y & 3;
  int l  = (ly & 1) ? (NLAT - 1 - (ly >> 1)) : (ly >> 1);   // heavy-first
  int c0 = blockIdx.x * NCOLS;
  int tid = threadIdx.x;
  bool act = tid < ACT;
  int w = 4 * tid;                   // local col base (act threads)

  const float* __restrict__ xh  = Xh  + (size_t)b * PLANE;
  const float* __restrict__ xuv = Xuv + (size_t)b * PLANE * 2;

  float ah0 = 0.f, ah1 = 0.f, ah2 = 0.f, ah3 = 0.f;
  float au0 = 0.f, au1 = 0.f, au2 = 0.f, au3 = 0.f;
  float av0 = 0.f, av1 = 0.f, av2 = 0.f, av3 = 0.f;

  for (int d = 0; d < ND; ++d) {
    int4 rm = rowmeta[l * ND + d];   // (iq*NLON, jlo, cnt4, off) — uniform
    int rcnt = rm.z;
    if (rcnt == 0) continue;
    const float* __restrict__ grh  = xh  + rm.x;
    const float* __restrict__ gruv = xuv + 2 * (size_t)rm.x;

    for (int tc = 0; tc < rcnt; tc += TCH) {
      int wcnt = min(TCH, rcnt - tc);        // multiple of 4
      int wlen = NCOLS - 1 + wcnt + 3;       // indices 0 .. 718+wcnt
      int gg = c0 + rm.y + tc;               // window start, unwrapped
      gg %= NLON; gg += (gg < 0) ? NLON : 0; // -> [0,1440)

      __syncthreads();                        // prior chunk's readers done
      for (int e = tid; e < wlen; e += BT) {
        int g = gg + e;                       // < 1440 + 984
        g -= (g >= NLON) ? NLON : 0;
        float  hh = grh[g];
        float2 uv = *(const float2*)(gruv + 2 * g);
        sh[e] = hh; su[e] = uv.x; sv[e] = uv.y;
      }
      for (int k = tid; k < wcnt; k += BT) swt[k] = tapw[rm.w + tc + k];
      __syncthreads();

      if (act) {
        float h0 = sh[w],     h1 = sh[w + 1], h2 = sh[w + 2];
        float u0 = su[w],     u1 = su[w + 1], u2 = su[w + 2];
        float v0 = sv[w],     v1 = sv[w + 1], v2 = sv[w + 2];
        for (int tg = 0; tg < wcnt; tg += 4) {
          float4 W0 = swt[tg], W1 = swt[tg + 1], W2 = swt[tg + 2], W3 = swt[tg + 3];
          int ix = w + tg + 3;
          float h3 = sh[ix], h4 = sh[ix + 1], h5 = sh[ix + 2], h6 = sh[ix + 3];
          float u3 = su[ix], u4 = su[ix + 1], u5 = su[ix + 2], u6 = su[ix + 3];
          float v3 = sv[ix], v4 = sv[ix + 1], v5 = sv[ix + 2], v6 = sv[ix + 3];
          // tap tg+0: cols 0..3 use elems (0,1,2,3)
          ah0 = fmaf(W0.z, u0, ah0); ah0 = fmaf(W0.w, v0, ah0);
          au0 = fmaf(W0.x, h0, au0); av0 = fmaf(W0.y, h0, av0);
          ah1 = fmaf(W0.z, u1, ah1); ah1 = fmaf(W0.w, v1, ah1);
          au1 = fmaf(W0.x, h1, au1); av1 = fmaf(W0.y, h1, av1);
          ah2 = fmaf(W0.z, u2, ah2); ah2 = fmaf(W0.w, v2, ah2);
          au2 = fmaf(W0.x, h2, au2); av2 = fmaf(W0.y, h2, av2);
          ah3 = fmaf(W0.z, u3, ah3); ah3 = fmaf(W0.w, v3, ah3);
          au3 = fmaf(W0.x, h3, au3); av3 = fmaf(W0.y, h3, av3);
          // tap tg+1: elems (1,2,3,4)
          ah0 = fmaf(W1.z, u1, ah0); ah0 = fmaf(W1.w, v1, ah0);
          au0 = fmaf(W1.x, h1, au0); av0 = fmaf(W1.y, h1, av0);
          ah1 = fmaf(W1.z, u2, ah1); ah1 = fmaf(W1.w, v2, ah1);
          au1 = fmaf(W1.x, h2, au1); av1 = fmaf(W1.y, h2, av1);
          ah2 = fmaf(W1.z, u3, ah2); ah2 = fmaf(W1.w, v3, ah2);
          au2 = fmaf(W1.x, h3, au2); av2 = fmaf(W1.y, h3, av2);
          ah3 = fmaf(W1.z, u4, ah3); ah3 = fmaf(W1.w, v4, ah3);
          au3 = fmaf(W1.x, h4, au3); av3 = fmaf(W1.y, h4, av3);
          // tap tg+2: elems (2,3,4,5)
          ah0 = fmaf(W2.z, u2, ah0); ah0 = fmaf(W2.w, v2, ah0);
          au0 = fmaf(W2.x, h2, au0); av0 = fmaf(W2.y, h2, av0);
          ah1 = fmaf(W2.z, u3, ah1); ah1 = fmaf(W2.w, v3, ah1);
          au1 = fmaf(W2.x, h3, au1); av1 = fmaf(W2.y, h3, av1);
          ah2 = fmaf(W2.z, u4, ah2); ah2 = fmaf(W2.w, v4, ah2);
          au2 = fmaf(W2.x, h4, au2); av2 = fmaf(W2.y, h4, av2);
          ah3 = fmaf(W2.z, u5, ah3); ah3 = fmaf(W2.w, v5, ah3);
          au3 = fmaf(W2.x, h5, au3); av3 = fmaf(W2.y, h5, av3);
          // tap tg+3: elems (3,4,5,6)
          ah0 = fmaf(W3.z, u3, ah0); ah0 = fmaf(W3.w, v3, ah0);
          au0 = fmaf(W3.x, h3, au0); av0 = fmaf(W3.y, h3, av0);
          ah1 = fmaf(W3.z, u4, ah1); ah1 = fmaf(W3.w, v4, ah1);
          au1 = fmaf(W3.x, h4, au1); av1 = fmaf(W3.y, h4, av1);
          ah2 = fmaf(W3.z, u5, ah2); ah2 = fmaf(W3.w, v5, ah2);
          au2 = fmaf(W3.x, h5, au2); av2 = fmaf(W3.y, h5, av2);
          ah3 = fmaf(W3.z, u6, ah3); ah3 = fmaf(W3.w, v6, ah3);
          au3 = fmaf(W3.x, h6, au3); av3 = fmaf(W3.y, h6, av3);
          // rotate window
          h0 = h4; h1 = h5; h2 = h6;
          u0 = u4; u1 = u5; u2 = u6;
          v0 = v4; v1 = v5; v2 = v6;
        }
      }
    }
  }

  // ---- epilogue: Coriolis + RK4 combine (own-point uv from global) ----
  if (act) {
    size_t ih  = (size_t)b * PLANE + (size_t)l * NLON + c0 + w;
    size_t iuv = 2 * ih;
    float f = fcor[l];
    float4 xa = *(const float4*)(Xuv + iuv);      // u0,v0,u1,v1
    float4 xb = *(const float4*)(Xuv + iuv + 4);  // u2,v2,u3,v3
    float kh0 = -ah0, kh1 = -ah1, kh2 = -ah2, kh3 = -ah3;
    float ku0 = fmaf(-f, xa.y, -au0), kv0 = fmaf(f, xa.x, -av0);
    float ku1 = fmaf(-f, xa.w, -au1), kv1 = fmaf(f, xa.z, -av1);
    float ku2 = fmaf(-f, xb.y, -au2), kv2 = fmaf(f, xb.x, -av2);
    float ku3 = fmaf(-f, xb.w, -au3), kv3 = fmaf(f, xb.z, -av3);

    if (mode == 0) {
      float4 s0 = *(const float4*)(S0h + ih);
      *(float4*)(Oh + ih) = make_float4(fmaf(cdt, kh0, s0.x), fmaf(cdt, kh1, s0.y),
                                        fmaf(cdt, kh2, s0.z), fmaf(cdt, kh3, s0.w));
      float4 sa = *(const float4*)(S0uv + iuv);
      float4 sb = *(const float4*)(S0uv + iuv + 4);
      *(float4*)(Ouv + iuv)     = make_float4(fmaf(cdt, ku0, sa.x), fmaf(cdt, kv0, sa.y),
                                              fmaf(cdt, ku1, sa.z), fmaf(cdt, kv1, sa.w));
      *(float4*)(Ouv + iuv + 4) = make_float4(fmaf(cdt, ku2, sb.x), fmaf(cdt, kv2, sb.y),
                                              fmaf(cdt, ku3, sb.z), fmaf(cdt, kv3, sb.w));
    } else {
      const float DT6 = DTSTEP / 6.0f;
      const float TH  = 1.0f / 3.0f;
      float4 xh3 = *(const float4*)(Xh + ih);   // X3 h at own cols
      float4 s0 = *(const float4*)(S0h + ih);
      float4 x1 = *(const float4*)(X1h + ih);
      float4 x2 = *(const float4*)(X2h + ih);
      *(float4*)(Oh + ih) = make_float4(
        TH * (x1.x + 2.f * x2.x + xh3.x - s0.x) + DT6 * kh0,
        TH * (x1.y + 2.f * x2.y + xh3.y - s0.y) + DT6 * kh1,
        TH * (x1.z + 2.f * x2.z + xh3.z - s0.z) + DT6 * kh2,
        TH * (x1.w + 2.f * x2.w + xh3.w - s0.w) + DT6 * kh3);
      float4 sa = *(const float4*)(S0uv + iuv);
      float4 sb = *(const float4*)(S0uv + iuv + 4);
      float4 xa1 = *(const float4*)(X1uv + iuv);
      float4 xb1 = *(const float4*)(X1uv + iuv + 4);
      float4 xa2 = *(const float4*)(X2uv + iuv);
      float4 xb2 = *(const float4*)(X2uv + iuv + 4);
      *(float4*)(Ouv + iuv) = make_float4(
        TH * (xa1.x + 2.f * xa2.x + xa.x - sa.x) + DT6 * ku0,
        TH * (xa1.y + 2.f * xa2.y + xa.y - sa.y) + DT6 * kv0,
        TH * (xa1.z + 2.f * xa2.z + xa.z - sa.z) + DT6 * ku1,
        TH * (xa1.w + 2.f * xa2.w + xa.w - sa.w) + DT6 * kv1);
      *(float4*)(Ouv + iuv + 4) = make_float4(
        TH * (xb1.x + 2.f * xb2.x + xb.x - sb.x) + DT6 * ku2,
        TH * (xb1.y + 2.f * xb2.y + xb.y - sb.y) + DT6 * kv2,
        TH * (xb1.z + 2.f * xb2.z + xb.z - sb.z) + DT6 * ku3,
        TH * (xb1.w + 2.f * xb2.w + xb.w - sb.w) + DT6 * kv3);
    }
  }
}

// ---------------------------------------------------------------------------
extern "C" void kernel_launch(void* const* d_in, const int* in_sizes, int n_in,
                              void* d_out, int out_size, void* d_ws, size_t ws_size,
                              hipStream_t stream)
{
  const float* h0   = (const float*)d_in[0];
  const float* uv0  = (const float*)d_in[1];
  const float* Kgc  = (const float*)d_in[2];
  const float* Kgs  = (const float*)d_in[3];
  const float* Kdc  = (const float*)d_in[4];
  const float* Kds  = (const float*)d_in[5];
  const float* fcor = (const float*)d_in[6];

  char* ws = (char*)d_ws;
  size_t pos = 0;
  auto carve = [&](size_t bytes) -> void* {
    void* p = ws + pos;
    pos += (bytes + 255) & ~(size_t)255;
    return p;
  };

  int*   jlo_a   = (int*)carve(sizeof(int) * NROWS);
  int*   cnt_a   = (int*)carve(sizeof(int) * NROWS);
  int*   off_a   = (int*)carve(sizeof(int) * NROWS);
  int4*  rowmeta = (int4*)carve(sizeof(int4) * NROWS);
  float* X1      = (float*)carve(sizeof(float) * 3 * (size_t)HVOL);
  float* X2      = (float*)carve(sizeof(float) * 3 * (size_t)HVOL);
  float* X3      = (float*)carve(sizeof(float) * 3 * (size_t)HVOL);
  float4* tapw   = (float4*)carve(sizeof(float4) * (size_t)TAPCAP);

  float* X1h = X1;  float* X1uv = X1 + HVOL;
  float* X2h = X2;  float* X2uv = X2 + HVOL;
  float* X3h = X3;  float* X3uv = X3 + HVOL;
  float* out_h  = (float*)d_out;          // [NB,1,NLAT,NLON]
  float* out_uv = (float*)d_out + HVOL;   // [NB,1,NLAT,NLON,2]

  support_kernel<<<NROWS, 64, 0, stream>>>(Kgc, Kgs, Kdc, Kds, jlo_a, cnt_a);
  scan_kernel<<<1, 256, 0, stream>>>(cnt_a, jlo_a, off_a, rowmeta, TAPCAP);
  fill_kernel<<<NROWS, 64, 0, stream>>>(Kgc, Kgs, Kdc, Kds, jlo_a, cnt_a, off_a,
                                        tapw, TAPCAP);

  dim3 gs(2, NLAT * NB);

  // stage 1: k1 from S0; X1 = S0 + dt/2 k1
  stage_kernel<<<gs, BT, 0, stream>>>(h0, uv0, h0, uv0, h0, uv0, h0, uv0, fcor,
                                      rowmeta, tapw, X1h, X1uv, 0.5f * DTSTEP, 0);
  // stage 2: k2 from X1; X2 = S0 + dt/2 k2
  stage_kernel<<<gs, BT, 0, stream>>>(X1h, X1uv, h0, uv0, h0, uv0, h0, uv0, fcor,
                                      rowmeta, tapw, X2h, X2uv, 0.5f * DTSTEP, 0);
  // stage 3: k3 from X2; X3 = S0 + dt k3
  stage_kernel<<<gs, BT, 0, stream>>>(X2h, X2uv, h0, uv0, h0, uv0, h0, uv0, fcor,
                                      rowmeta, tapw, X3h, X3uv, DTSTEP, 0);
  // stage 4: k4 from X3; out = (X1 + 2 X2 + X3 - S0)/3 + dt/6 k4
  stage_kernel<<<gs, BT, 0, stream>>>(X3h, X3uv, h0, uv0, X1h, X1uv, X2h, X2uv, fcor,
                                      rowmeta, tapw, out_h, out_uv, 0.0f, 1);
}